// Round 13
// baseline (247.179 us; speedup 1.0000x reference)
//
#include <hip/hip_runtime.h>
#include <cstdint>
#include <cstddef>
#include <math.h>

#define B_   2
#define T_   2048
#define DM   1024
#define NH   16
#define DH   64
#define DC1  384
#define DCC  256
#define DR   32
#define BT   (B_*T_)
#define DQK  96      // DH + DR

typedef __bf16 bf16x8 __attribute__((ext_vector_type(8)));
typedef __bf16 bf16x4 __attribute__((ext_vector_type(4)));
typedef float  f32x4  __attribute__((ext_vector_type(4)));
#define MFMA16(a,b,c) __builtin_amdgcn_mfma_f32_16x16x32_bf16((a),(b),(c),0,0,0)

__device__ __forceinline__ void gld16(const __bf16* g, __bf16* l) {
  __builtin_amdgcn_global_load_lds(
      (const __attribute__((address_space(1))) void*)g,
      (__attribute__((address_space(3))) void*)l, 16, 0, 0);
}

// ---------------------------------------------------------------------------
// Multi-GEMM, single-barrier double-buffered gld16 pipeline.
// Each desc: C[M,N] = A[M,K] @ Bt[N,K]^T, TMxTN tile, BK=32.
// Wave grid 2x2; wave tile (TM/2)x(TN/2). TM,TN in {64,128}.
// ---------------------------------------------------------------------------
struct GemmDesc {
  const __bf16* A;
  const __bf16* Bt;
  void* C;
  int lda, ldb, ldc, K, Nvalid, ntx, blk0;
};
struct GemmBatch { GemmDesc d[4]; int nd; };

template<typename CT, int TM, int TN>
__global__ __launch_bounds__(256) void gemm_multi(GemmBatch gb) {
  constexpr int MT  = TM / 32;          // MFMA m-tiles per wave
  constexpr int NT  = TN / 32;          // MFMA n-tiles per wave
  constexpr int APW = (TM * 4) / 256;   // A gld16 issues per wave
  constexpr int BPW = (TN * 4) / 256;   // B gld16 issues per wave
  __shared__ __align__(16) __bf16 As[2][TM * 32];
  __shared__ __align__(16) __bf16 Bs[2][TN * 32];
  const int bid = blockIdx.x;
  int di = gb.nd - 1;
  while (di > 0 && bid < gb.d[di].blk0) di--;
  const GemmDesc D = gb.d[di];
  const int local = bid - D.blk0;
  const int by = local / D.ntx, bx = local - by * D.ntx;
  const int m0 = by * TM, n0 = bx * TN;

  const int tid = threadIdx.x;
  const int w = tid >> 6, l = tid & 63;
  const int g = l >> 4, ln = l & 15;
  const int wm = w >> 1, wn = w & 1;

  const __bf16* gA[APW]; int aoff[APW];
  #pragma unroll
  for (int i = 0; i < APW; i++) {
    int slot = w * (APW * 64) + i * 64 + l;            // per-lane (global)
    gA[i] = D.A + (size_t)(m0 + (slot >> 2)) * D.lda + (slot & 3) * 8;
    aoff[i] = (w * (APW * 64) + i * 64) * 8;           // wave-uniform (LDS)
  }
  const __bf16* gB[BPW]; int boff[BPW];
  #pragma unroll
  for (int i = 0; i < BPW; i++) {
    int slot = w * (BPW * 64) + i * 64 + l;
    int bn = n0 + (slot >> 2); if (bn >= D.Nvalid) bn = D.Nvalid - 1;
    gB[i] = D.Bt + (size_t)bn * D.ldb + (slot & 3) * 8;
    boff[i] = (w * (BPW * 64) + i * 64) * 8;
  }

  f32x4 acc[MT][NT];
  #pragma unroll
  for (int i = 0; i < MT; i++)
    #pragma unroll
    for (int j = 0; j < NT; j++) acc[i][j] = (f32x4){0.f, 0.f, 0.f, 0.f};

  // prime buffer 0
  #pragma unroll
  for (int i = 0; i < APW; i++) gld16(gA[i], As[0] + aoff[i]);
  #pragma unroll
  for (int i = 0; i < BPW; i++) gld16(gB[i], Bs[0] + boff[i]);

  const int niter = D.K >> 5;
  int p = 0;
  for (int it = 0; it < niter; ++it) {
    __syncthreads();            // drains vmcnt -> buf[p] ready
    if (it + 1 < niter) {       // prefetch next tile into buf[p^1]
      const int ko = (it + 1) * 32;
      #pragma unroll
      for (int i = 0; i < APW; i++) gld16(gA[i] + ko, As[p ^ 1] + aoff[i]);
      #pragma unroll
      for (int i = 0; i < BPW; i++) gld16(gB[i] + ko, Bs[p ^ 1] + boff[i]);
    }
    bf16x8 af[MT], bfr[NT];
    #pragma unroll
    for (int mt = 0; mt < MT; mt++)
      af[mt] = *(const bf16x8*)(As[p] + (wm * (TM/2) + mt * 16 + ln) * 32 + g * 8);
    #pragma unroll
    for (int nt = 0; nt < NT; nt++)
      bfr[nt] = *(const bf16x8*)(Bs[p] + (wn * (TN/2) + nt * 16 + ln) * 32 + g * 8);
    #pragma unroll
    for (int mt = 0; mt < MT; mt++)
      #pragma unroll
      for (int nt = 0; nt < NT; nt++)
        acc[mt][nt] = MFMA16(af[mt], bfr[nt], acc[mt][nt]);
    p ^= 1;
  }

  CT* C = (CT*)D.C;
  #pragma unroll
  for (int mt = 0; mt < MT; mt++)
    #pragma unroll
    for (int r = 0; r < 4; r++) {
      int m = m0 + wm * (TM/2) + mt * 16 + g * 4 + r;
      #pragma unroll
      for (int nt = 0; nt < NT; nt++) {
        int n = n0 + wn * (TN/2) + nt * 16 + ln;
        if (n < D.Nvalid) C[(size_t)m * D.ldc + n] = (CT)acc[mt][nt][r];
      }
    }
}

// ---------------------------------------------------------------------------
// Fused weight prep: 8 matrices fp32 [K,N] -> bf16 transposed [N,K].
// ---------------------------------------------------------------------------
struct TDescs {
  const float* src[8];
  __bf16* dst[8];
  int K[8];
  int N[8];
  int t0[9];
};

__global__ __launch_bounds__(256) void transpose_cast_all(TDescs td) {
  __shared__ float t[32][33];
  int bx = blockIdx.x;
  int i = 7;
  while (bx < td.t0[i]) i--;
  int local = bx - td.t0[i];
  int ntn = td.N[i] >> 5;
  int kt = local / ntn;
  int nt = local - kt * ntn;
  const int ks = kt * 32, ns = nt * 32;
  const float* src = td.src[i];
  __bf16* dst = td.dst[i];
  const int K = td.K[i], N = td.N[i];
  const int tx = threadIdx.x, ty = threadIdx.y;
  #pragma unroll
  for (int r = 0; r < 4; r++)
    t[ty + r * 8][tx] = src[(size_t)(ks + ty + r * 8) * N + ns + tx];
  __syncthreads();
  #pragma unroll
  for (int r = 0; r < 4; r++)
    dst[(size_t)(ns + ty + r * 8) * K + ks + tx] = (__bf16)t[tx][ty + r * 8];
  (void)K;
}

__global__ __launch_bounds__(256) void cast_f32_bf16(
    const float* __restrict__ src, __bf16* __restrict__ dst) {
  int i = (blockIdx.x * 256 + threadIdx.x) * 4;
  float4 v = *(const float4*)(src + i);
  bf16x4 o = { (__bf16)v.x, (__bf16)v.y, (__bf16)v.z, (__bf16)v.w };
  *(bf16x4*)(dst + i) = o;
}

// ---------------------------------------------------------------------------
// Assemble: per (row, head) wave -> RoPE + concat + RMS-norm.
// ---------------------------------------------------------------------------
__global__ __launch_bounds__(256) void assemble_qk(
    const __bf16* __restrict__ qsqr,  // [BT][1536]: qs | qr
    const __bf16* __restrict__ kv,    // [BT][1024]: ks
    const __bf16* __restrict__ cqkr,  // [BT][672]: kr at cols 640..671
    __bf16* __restrict__ qb, __bf16* __restrict__ kb) {
  int wid  = (blockIdx.x * blockDim.x + threadIdx.x) >> 6;
  int lane = threadIdx.x & 63;
  int h   = wid & (NH - 1);
  int row = wid >> 4;
  int b   = row >> 11;
  int t   = row & (T_ - 1);

  float v0q = (float)qsqr[(size_t)row * 1536 + h * DH + lane];
  float v0k = (float)kv[(size_t)row * 1024 + h * DH + lane];
  float v1q = 0.f, v1k = 0.f;
  if (lane < DR) {
    int j  = lane;
    int jj = j & 15;
    float invf = powf(10000.f, -(float)jj / 16.f);
    float ang  = (float)t * invf;
    float s, c;
    sincosf(ang, &s, &c);
    float qx1 = (float)qsqr[(size_t)row * 1536 + 1024 + h * DR + jj];
    float qx2 = (float)qsqr[(size_t)row * 1536 + 1024 + h * DR + 16 + jj];
    float kx1 = (float)cqkr[(size_t)row * 672 + 640 + jj];
    float kx2 = (float)cqkr[(size_t)row * 672 + 640 + 16 + jj];
    if (j < 16) { v1q = qx1 * c - qx2 * s; v1k = kx1 * c - kx2 * s; }
    else        { v1q = qx1 * s + qx2 * c; v1k = kx1 * s + kx2 * c; }
  }
  float ssq = v0q * v0q + v1q * v1q;
  float ssk = v0k * v0k + v1k * v1k;
  #pragma unroll
  for (int off = 32; off; off >>= 1) {
    ssq += __shfl_xor(ssq, off);
    ssk += __shfl_xor(ssk, off);
  }
  float sq = rsqrtf(ssq / 96.f + 1e-6f);
  float sk = rsqrtf(ssk / 96.f + 1e-6f);
  size_t obase = ((size_t)(b * NH + h) * T_ + t) * DQK;
  qb[obase + lane] = (__bf16)(v0q * sq);
  kb[obase + lane] = (__bf16)(v0k * sk);
  if (lane < DR) {
    qb[obase + DH + lane] = (__bf16)(v1q * sq);
    kb[obase + DH + lane] = (__bf16)(v1k * sk);
  }
}

// ---------------------------------------------------------------------------
// Fixed-max MFMA flash attention (causal), PAIRED q-tiles (r7/r9 structure:
// TWO barriers per K-tile, single-buffered K/V LDS, per-tile PV loops).
// Block bx: q-tiles (bx, 31-bx) -> uniform 33 K-iters/block.
// |score| <= sqrt(96) (RMS-normed q,k) => plain exp, no running max.
// Grid (16, 32) = 512 blocks. LDS = 40 KB.
// ---------------------------------------------------------------------------
#define KS_STR 104   // K LDS row stride
#define VT_STR 72    // V^T / P row stride
__global__ __launch_bounds__(256) void flash_mfma(
    const __bf16* __restrict__ qg, const __bf16* __restrict__ kg,
    const __bf16* __restrict__ vt,  // [b*1024 + h*64 + d][T_]  (V^T)
    __bf16* __restrict__ ao) {
  __shared__ __align__(16) __bf16 Ksh[64 * KS_STR];      // 13312 B
  __shared__ __align__(16) __bf16 Vth[64 * VT_STR];      //  9216 B
  __shared__ __align__(16) __bf16 Psh[8 * 16 * VT_STR];  // 18432 B

  const int hb = blockIdx.y;
  const int bb = hb >> 4, h = hb & 15;
  const int ta = blockIdx.x;                 // light tile 0..15
  const int tb = (T_ / 64 - 1) - ta;         // heavy tile 31..16
  const int w    = threadIdx.x >> 6;
  const int lane = threadIdx.x & 63;
  const int g    = lane >> 4;
  const int ln   = lane & 15;
  const int qwa = ta * 64 + w * 16;
  const int qwb = tb * 64 + w * 16;
  const float scale = 0.10206207261596577f;  // 1/sqrt(96)
  const size_t hbT = (size_t)hb * T_;
  const __bf16* vrow = vt + (size_t)(bb * 1024 + h * 64) * T_;

  int krow[3], kcol[3], vr[2], vc[2];
  #pragma unroll
  for (int it = 0; it < 3; it++) {
    int slot = threadIdx.x + it * 256;
    krow[it] = slot / 12; kcol[it] = slot % 12;
  }
  #pragma unroll
  for (int it = 0; it < 2; it++) {
    int slot = threadIdx.x + it * 256;
    vr[it] = slot >> 3; vc[it] = slot & 7;
  }

  bf16x8 qfa[3], qfb[3];
  #pragma unroll
  for (int s = 0; s < 3; s++) {
    qfa[s] = *(const bf16x8*)(qg + (hbT + qwa + ln) * DQK + s * 32 + g * 8);
    qfb[s] = *(const bf16x8*)(qg + (hbT + qwb + ln) * DQK + s * 32 + g * 8);
  }

  f32x4 oa[4], ob[4];
  #pragma unroll
  for (int nt = 0; nt < 4; nt++) {
    oa[nt] = (f32x4){0.f, 0.f, 0.f, 0.f};
    ob[nt] = (f32x4){0.f, 0.f, 0.f, 0.f};
  }
  float la[4] = {}, lb[4] = {};

  __bf16* Pb = Psh + w * 16 * VT_STR;
  __bf16* Pa = Psh + (4 + w) * 16 * VT_STR;
  const int kmax = (tb + 1) * 64;            // b is the longer range

  bf16x8 kreg[3], vreg[2];
  #pragma unroll
  for (int it = 0; it < 3; it++)
    kreg[it] = *(const bf16x8*)(kg + (hbT + krow[it]) * DQK + kcol[it] * 8);
  #pragma unroll
  for (int it = 0; it < 2; it++)
    vreg[it] = *(const bf16x8*)(vrow + (size_t)vr[it] * T_ + vc[it] * 8);

  for (int k0 = 0; k0 < kmax; k0 += 64) {
    __syncthreads();   // previous compute done reading Ksh/Vth
    #pragma unroll
    for (int it = 0; it < 3; it++)
      *(bf16x8*)(Ksh + krow[it] * KS_STR + kcol[it] * 8) = kreg[it];
    #pragma unroll
    for (int it = 0; it < 2; it++)
      *(bf16x8*)(Vth + vr[it] * VT_STR + vc[it] * 8) = vreg[it];
    __syncthreads();
    if (k0 + 64 < kmax) {   // prefetch next tile into regs (hidden by compute)
      #pragma unroll
      for (int it = 0; it < 3; it++)
        kreg[it] = *(const bf16x8*)(kg + (hbT + k0 + 64 + krow[it]) * DQK + kcol[it] * 8);
      #pragma unroll
      for (int it = 0; it < 2; it++)
        vreg[it] = *(const bf16x8*)(vrow + (size_t)vr[it] * T_ + k0 + 64 + vc[it] * 8);
    }

    const bool ca = (k0 <= qwa + 15);   // light tile active (wave-uniform)

    f32x4 sa[4], sb[4];
    #pragma unroll
    for (int ks = 0; ks < 4; ks++) {
      sa[ks] = (f32x4){0.f, 0.f, 0.f, 0.f};
      sb[ks] = (f32x4){0.f, 0.f, 0.f, 0.f};
    }
    if (ca) {
      #pragma unroll
      for (int s = 0; s < 3; s++)
        #pragma unroll
        for (int ks = 0; ks < 4; ks++) {
          bf16x8 kf = *(const bf16x8*)(Ksh + (ks * 16 + ln) * KS_STR + s * 32 + g * 8);
          sb[ks] = MFMA16(qfb[s], kf, sb[ks]);
          sa[ks] = MFMA16(qfa[s], kf, sa[ks]);
        }
    } else {
      #pragma unroll
      for (int s = 0; s < 3; s++)
        #pragma unroll
        for (int ks = 0; ks < 4; ks++) {
          bf16x8 kf = *(const bf16x8*)(Ksh + (ks * 16 + ln) * KS_STR + s * 32 + g * 8);
          sb[ks] = MFMA16(qfb[s], kf, sb[ks]);
        }
    }

    // tile b: exp + P + PV (always active: k0 <= tb*64 <= qwb+15)
    {
      const bool diag = (k0 + 63 > qwb);
      #pragma unroll
      for (int ks = 0; ks < 4; ks++)
        #pragma unroll
        for (int r = 0; r < 4; r++) {
          float p = __expf(sb[ks][r] * scale);
          if (diag) {
            int q   = qwb + g * 4 + r;
            int key = k0 + ks * 16 + ln;
            if (key > q) p = 0.f;
          }
          lb[r] += p;
          Pb[(g * 4 + r) * VT_STR + ks * 16 + ln] = (__bf16)p;
        }
      #pragma unroll
      for (int ks2 = 0; ks2 < 2; ks2++) {
        bf16x8 pf = *(const bf16x8*)(Pb + ln * VT_STR + ks2 * 32 + g * 8);
        #pragma unroll
        for (int nt = 0; nt < 4; nt++) {
          bf16x8 vf = *(const bf16x8*)(Vth + (nt * 16 + ln) * VT_STR + ks2 * 32 + g * 8);
          ob[nt] = MFMA16(pf, vf, ob[nt]);
        }
      }
    }

    // tile a: exp + P + PV (only while in range)
    if (ca) {
      const bool diag = (k0 + 63 > qwa);
      #pragma unroll
      for (int ks = 0; ks < 4; ks++)
        #pragma unroll
        for (int r = 0; r < 4; r++) {
          float p = __expf(sa[ks][r] * scale);
          if (diag) {
            int q   = qwa + g * 4 + r;
            int key = k0 + ks * 16 + ln;
            if (key > q) p = 0.f;
          }
          la[r] += p;
          Pa[(g * 4 + r) * VT_STR + ks * 16 + ln] = (__bf16)p;
        }
      #pragma unroll
      for (int ks2 = 0; ks2 < 2; ks2++) {
        bf16x8 pf = *(const bf16x8*)(Pa + ln * VT_STR + ks2 * 32 + g * 8);
        #pragma unroll
        for (int nt = 0; nt < 4; nt++) {
          bf16x8 vf = *(const bf16x8*)(Vth + (nt * 16 + ln) * VT_STR + ks2 * 32 + g * 8);
          oa[nt] = MFMA16(pf, vf, oa[nt]);
        }
      }
    }
  }

  // reduce l across the 16 ln-lanes (g bits untouched by xor 1/2/4/8)
  float lia[4], lib[4];
  #pragma unroll
  for (int r = 0; r < 4; r++) {
    float s = la[r];
    s += __shfl_xor(s, 1); s += __shfl_xor(s, 2);
    s += __shfl_xor(s, 4); s += __shfl_xor(s, 8);
    lia[r] = 1.0f / s;
    float u = lb[r];
    u += __shfl_xor(u, 1); u += __shfl_xor(u, 2);
    u += __shfl_xor(u, 4); u += __shfl_xor(u, 8);
    lib[r] = 1.0f / u;
  }

  #pragma unroll
  for (int nt = 0; nt < 4; nt++)
    #pragma unroll
    for (int r = 0; r < 4; r++) {
      int qa = qwa + g * 4 + r;
      int qb2 = qwb + g * 4 + r;
      ao[(size_t)(bb * T_ + qa) * DM + h * DH + nt * 16 + ln] =
          (__bf16)(oa[nt][r] * lia[r]);
      ao[(size_t)(bb * T_ + qb2) * DM + h * DH + nt * 16 + ln] =
          (__bf16)(ob[nt][r] * lib[r]);
    }
}

// ---------------------------------------------------------------------------
extern "C" void kernel_launch(void* const* d_in, const int* in_sizes, int n_in,
                              void* d_out, int out_size, void* d_ws, size_t ws_size,
                              hipStream_t stream) {
  const float* x     = (const float*)d_in[0];
  const float* w_dq  = (const float*)d_in[1];
  const float* w_uq  = (const float*)d_in[2];
  const float* w_rq  = (const float*)d_in[3];
  const float* w_dkv = (const float*)d_in[4];
  const float* w_rk  = (const float*)d_in[5];
  const float* w_uk  = (const float*)d_in[6];
  const float* w_uv  = (const float*)d_in[7];
  const float* w_o   = (const float*)d_in[8];
  float* out = (float*)d_out;

  __bf16* p = (__bf16*)d_ws;
  __bf16* xb   = p;  p += (size_t)BT * DM;
  __bf16* B1t  = p;  p += (size_t)672 * 1024;
  __bf16* B2t  = p;  p += (size_t)1536 * 384;
  __bf16* B3t  = p;  p += (size_t)2048 * 256;   // w_uk^T | w_uv^T
  __bf16* B4t  = p;  p += (size_t)1024 * 1024;
  __bf16* cqkr = p;  p += (size_t)BT * 672;     // c_q | c_kv | kr
  __bf16* qsqr = p;  p += (size_t)BT * 1536;    // qs | qr
  __bf16* kv   = p;  p += (size_t)BT * 1024;    // ks
  __bf16* vt   = p;  p += (size_t)BT * 1024;    // V^T [b*1024+h*64+d][T]
  __bf16* qb   = p;  p += (size_t)B_ * NH * T_ * DQK;
  __bf16* kb   = p;  p += (size_t)B_ * NH * T_ * DQK;
  __bf16* aob  = xb;   // xb dead after G1

  // Prep: cast x; fused transpose of all 8 weights
  cast_f32_bf16<<<(BT * DM) / 1024, 256, 0, stream>>>(x, xb);
  {
    TDescs td;
    const float* srcs[8] = {w_dq, w_dkv, w_rk, w_uq, w_rq, w_uk, w_uv, w_o};
    __bf16* dsts[8] = {B1t, B1t + (size_t)384 * 1024, B1t + (size_t)640 * 1024,
                       B2t, B2t + (size_t)1024 * 384,
                       B3t, B3t + (size_t)1024 * 256, B4t};
    int Ks[8] = {1024, 1024, 1024, 384, 384, 256, 256, 1024};
    int Ns[8] = {384, 256, 32, 1024, 512, 1024, 1024, 1024};
    int acc = 0;
    for (int i = 0; i < 8; i++) {
      td.src[i] = srcs[i]; td.dst[i] = dsts[i];
      td.K[i] = Ks[i]; td.N[i] = Ns[i];
      td.t0[i] = acc;
      acc += (Ks[i] / 32) * (Ns[i] / 32);
    }
    td.t0[8] = acc;
    transpose_cast_all<<<acc, dim3(32, 8), 0, stream>>>(td);
  }

  // G1: cqkr = xb @ B1t^T   (64x64 tiles: 704 blocks)
  {
    GemmBatch g; g.nd = 1;
    g.d[0] = GemmDesc{xb, B1t, (void*)cqkr, DM, 1024, 672, 1024, 672, 11, 0};
    gemm_multi<__bf16, 64, 64><<<704, 256, 0, stream>>>(g);
  }
  // Fused: G2 (qsqr), G3 (ks), VT batch 0/1   (64x128 tiles: 1792 blocks)
  {
    GemmBatch g; g.nd = 4;
    g.d[0] = GemmDesc{cqkr, B2t, (void*)qsqr, 672, 384, 1536, 384, 1536, 12, 0};
    g.d[1] = GemmDesc{cqkr + 384, B3t, (void*)kv, 672, 256, 1024, 256, 1024, 8, 768};
    g.d[2] = GemmDesc{B3t + (size_t)1024 * 256, cqkr + 384, (void*)vt,
                      256, 672, T_, 256, T_, 16, 1280};
    g.d[3] = GemmDesc{B3t + (size_t)1024 * 256, cqkr + (size_t)T_ * 672 + 384,
                      (void*)(vt + (size_t)1024 * T_), 256, 672, T_, 256, T_, 16, 1536};
    gemm_multi<__bf16, 64, 128><<<1792, 256, 0, stream>>>(g);
  }

  // RoPE + concat + RMS-norm
  assemble_qk<<<(BT * NH) / 4, 256, 0, stream>>>(qsqr, kv, cqkr, qb, kb);

  // Paired-tile fixed-max causal MFMA flash attention -> bf16 ao
  flash_mfma<<<dim3(T_ / 128, B_ * NH), 256, 0, stream>>>(qb, kb, vt, aob);

  // G4: out = aob @ B4t^T  (fp32 out, 64x64 tiles: 1024 blocks)
  {
    GemmBatch g; g.nd = 1;
    g.d[0] = GemmDesc{aob, B4t, (void*)out, DM, 1024, DM, 1024, 1024, 16, 0};
    gemm_multi<float, 64, 64><<<1024, 256, 0, stream>>>(g);
  }
}

// Round 14
// 240.668 us; speedup vs baseline: 1.0271x; 1.0271x over previous
//
#include <hip/hip_runtime.h>
#include <cstdint>
#include <cstddef>
#include <math.h>

#define B_   2
#define T_   2048
#define DM   1024
#define NH   16
#define DH   64
#define DC1  384
#define DCC  256
#define DR   32
#define BT   (B_*T_)
#define DQK  96      // DH + DR

typedef __bf16 bf16x8 __attribute__((ext_vector_type(8)));
typedef __bf16 bf16x4 __attribute__((ext_vector_type(4)));
typedef float  f32x4  __attribute__((ext_vector_type(4)));
#define MFMA16(a,b,c) __builtin_amdgcn_mfma_f32_16x16x32_bf16((a),(b),(c),0,0,0)

__device__ __forceinline__ void gld16(const __bf16* g, __bf16* l) {
  __builtin_amdgcn_global_load_lds(
      (const __attribute__((address_space(1))) void*)g,
      (__attribute__((address_space(3))) void*)l, 16, 0, 0);
}

// ---------------------------------------------------------------------------
// Multi-GEMM, single-barrier double-buffered gld16 pipeline, BK=64.
// BK is two 32-col panels so LDS rows stay gld16-contiguous (32 elems/row,
// 64 B -> all fragment accesses 16B-aligned). PROVEN CORRECT: r10/r11 (this
// GEMM) vs r12 (BK=32) produced bit-identical outputs.
// Each desc: C[M,N] = A[M,K] @ Bt[N,K]^T, TMxTN tile. Wave grid 2x2.
// K must be a multiple of 64.
// ---------------------------------------------------------------------------
struct GemmDesc {
  const __bf16* A;
  const __bf16* Bt;
  void* C;
  int lda, ldb, ldc, K, Nvalid, ntx, blk0;
};
struct GemmBatch { GemmDesc d[4]; int nd; };

template<typename CT, int TM, int TN>
__global__ __launch_bounds__(256) void gemm_multi(GemmBatch gb) {
  constexpr int MT  = TM / 32;          // MFMA m-tiles per wave
  constexpr int NT  = TN / 32;          // MFMA n-tiles per wave
  constexpr int APW = (TM * 4) / 256;   // gld16 per wave per 32-panel (A)
  constexpr int BPW = (TN * 4) / 256;   // gld16 per wave per 32-panel (B)
  __shared__ __align__(16) __bf16 As[4 * TM * 32];   // [buf][panel]
  __shared__ __align__(16) __bf16 Bs[4 * TN * 32];
  const int bid = blockIdx.x;
  int di = gb.nd - 1;
  while (di > 0 && bid < gb.d[di].blk0) di--;
  const GemmDesc D = gb.d[di];
  const int local = bid - D.blk0;
  const int by = local / D.ntx, bx = local - by * D.ntx;
  const int m0 = by * TM, n0 = bx * TN;

  const int tid = threadIdx.x;
  const int w = tid >> 6, l = tid & 63;
  const int g = l >> 4, ln = l & 15;
  const int wm = w >> 1, wn = w & 1;

  const __bf16* gA[APW]; int aoff[APW];
  #pragma unroll
  for (int i = 0; i < APW; i++) {
    int slot = w * (APW * 64) + i * 64 + l;            // per-lane (global)
    gA[i] = D.A + (size_t)(m0 + (slot >> 2)) * D.lda + (slot & 3) * 8;
    aoff[i] = (w * (APW * 64) + i * 64) * 8;           // wave-uniform (LDS)
  }
  const __bf16* gB[BPW]; int boff[BPW];
  #pragma unroll
  for (int i = 0; i < BPW; i++) {
    int slot = w * (BPW * 64) + i * 64 + l;
    int bn = n0 + (slot >> 2); if (bn >= D.Nvalid) bn = D.Nvalid - 1;
    gB[i] = D.Bt + (size_t)bn * D.ldb + (slot & 3) * 8;
    boff[i] = (w * (BPW * 64) + i * 64) * 8;
  }

  f32x4 acc[MT][NT];
  #pragma unroll
  for (int i = 0; i < MT; i++)
    #pragma unroll
    for (int j = 0; j < NT; j++) acc[i][j] = (f32x4){0.f, 0.f, 0.f, 0.f};

  // prime buffer 0 (both panels)
  #pragma unroll
  for (int ch = 0; ch < 2; ch++) {
    #pragma unroll
    for (int i = 0; i < APW; i++)
      gld16(gA[i] + ch * 32, As + ch * TM * 32 + aoff[i]);
    #pragma unroll
    for (int i = 0; i < BPW; i++)
      gld16(gB[i] + ch * 32, Bs + ch * TN * 32 + boff[i]);
  }

  const int nper = D.K >> 6;
  int p = 0;
  for (int it = 0; it < nper; ++it) {
    __syncthreads();            // drains vmcnt -> buf[p] ready
    if (it + 1 < nper) {        // prefetch next 64-K period into buf[p^1]
      const int ko = (it + 1) * 64;
      #pragma unroll
      for (int ch = 0; ch < 2; ch++) {
        #pragma unroll
        for (int i = 0; i < APW; i++)
          gld16(gA[i] + ko + ch * 32, As + ((p ^ 1) * 2 + ch) * TM * 32 + aoff[i]);
        #pragma unroll
        for (int i = 0; i < BPW; i++)
          gld16(gB[i] + ko + ch * 32, Bs + ((p ^ 1) * 2 + ch) * TN * 32 + boff[i]);
      }
    }
    #pragma unroll
    for (int ch = 0; ch < 2; ch++) {
      bf16x8 af[MT], bfr[NT];
      #pragma unroll
      for (int mt = 0; mt < MT; mt++)
        af[mt] = *(const bf16x8*)(As + (p * 2 + ch) * TM * 32 +
                                  (wm * (TM/2) + mt * 16 + ln) * 32 + g * 8);
      #pragma unroll
      for (int nt = 0; nt < NT; nt++)
        bfr[nt] = *(const bf16x8*)(Bs + (p * 2 + ch) * TN * 32 +
                                   (wn * (TN/2) + nt * 16 + ln) * 32 + g * 8);
      #pragma unroll
      for (int mt = 0; mt < MT; mt++)
        #pragma unroll
        for (int nt = 0; nt < NT; nt++)
          acc[mt][nt] = MFMA16(af[mt], bfr[nt], acc[mt][nt]);
    }
    p ^= 1;
  }

  CT* C = (CT*)D.C;
  #pragma unroll
  for (int mt = 0; mt < MT; mt++)
    #pragma unroll
    for (int r = 0; r < 4; r++) {
      int m = m0 + wm * (TM/2) + mt * 16 + g * 4 + r;
      #pragma unroll
      for (int nt = 0; nt < NT; nt++) {
        int n = n0 + wn * (TN/2) + nt * 16 + ln;
        if (n < D.Nvalid) C[(size_t)m * D.ldc + n] = (CT)acc[mt][nt][r];
      }
    }
}

// ---------------------------------------------------------------------------
// Fused weight prep: 8 matrices fp32 [K,N] -> bf16 transposed [N,K].
// ---------------------------------------------------------------------------
struct TDescs {
  const float* src[8];
  __bf16* dst[8];
  int K[8];
  int N[8];
  int t0[9];
};

__global__ __launch_bounds__(256) void transpose_cast_all(TDescs td) {
  __shared__ float t[32][33];
  int bx = blockIdx.x;
  int i = 7;
  while (bx < td.t0[i]) i--;
  int local = bx - td.t0[i];
  int ntn = td.N[i] >> 5;
  int kt = local / ntn;
  int nt = local - kt * ntn;
  const int ks = kt * 32, ns = nt * 32;
  const float* src = td.src[i];
  __bf16* dst = td.dst[i];
  const int K = td.K[i], N = td.N[i];
  const int tx = threadIdx.x, ty = threadIdx.y;
  #pragma unroll
  for (int r = 0; r < 4; r++)
    t[ty + r * 8][tx] = src[(size_t)(ks + ty + r * 8) * N + ns + tx];
  __syncthreads();
  #pragma unroll
  for (int r = 0; r < 4; r++)
    dst[(size_t)(ns + ty + r * 8) * K + ks + tx] = (__bf16)t[tx][ty + r * 8];
  (void)K;
}

__global__ __launch_bounds__(256) void cast_f32_bf16(
    const float* __restrict__ src, __bf16* __restrict__ dst) {
  int i = (blockIdx.x * 256 + threadIdx.x) * 4;
  float4 v = *(const float4*)(src + i);
  bf16x4 o = { (__bf16)v.x, (__bf16)v.y, (__bf16)v.z, (__bf16)v.w };
  *(bf16x4*)(dst + i) = o;
}

// ---------------------------------------------------------------------------
// Assemble: per (row, head) wave -> RoPE + concat + RMS-norm.
// ---------------------------------------------------------------------------
__global__ __launch_bounds__(256) void assemble_qk(
    const __bf16* __restrict__ qsqr,  // [BT][1536]: qs | qr
    const __bf16* __restrict__ kv,    // [BT][1024]: ks
    const __bf16* __restrict__ cqkr,  // [BT][672]: kr at cols 640..671
    __bf16* __restrict__ qb, __bf16* __restrict__ kb) {
  int wid  = (blockIdx.x * blockDim.x + threadIdx.x) >> 6;
  int lane = threadIdx.x & 63;
  int h   = wid & (NH - 1);
  int row = wid >> 4;
  int b   = row >> 11;
  int t   = row & (T_ - 1);

  float v0q = (float)qsqr[(size_t)row * 1536 + h * DH + lane];
  float v0k = (float)kv[(size_t)row * 1024 + h * DH + lane];
  float v1q = 0.f, v1k = 0.f;
  if (lane < DR) {
    int j  = lane;
    int jj = j & 15;
    float invf = powf(10000.f, -(float)jj / 16.f);
    float ang  = (float)t * invf;
    float s, c;
    sincosf(ang, &s, &c);
    float qx1 = (float)qsqr[(size_t)row * 1536 + 1024 + h * DR + jj];
    float qx2 = (float)qsqr[(size_t)row * 1536 + 1024 + h * DR + 16 + jj];
    float kx1 = (float)cqkr[(size_t)row * 672 + 640 + jj];
    float kx2 = (float)cqkr[(size_t)row * 672 + 640 + 16 + jj];
    if (j < 16) { v1q = qx1 * c - qx2 * s; v1k = kx1 * c - kx2 * s; }
    else        { v1q = qx1 * s + qx2 * c; v1k = kx1 * s + kx2 * c; }
  }
  float ssq = v0q * v0q + v1q * v1q;
  float ssk = v0k * v0k + v1k * v1k;
  #pragma unroll
  for (int off = 32; off; off >>= 1) {
    ssq += __shfl_xor(ssq, off);
    ssk += __shfl_xor(ssk, off);
  }
  float sq = rsqrtf(ssq / 96.f + 1e-6f);
  float sk = rsqrtf(ssk / 96.f + 1e-6f);
  size_t obase = ((size_t)(b * NH + h) * T_ + t) * DQK;
  qb[obase + lane] = (__bf16)(v0q * sq);
  kb[obase + lane] = (__bf16)(v0k * sk);
  if (lane < DR) {
    qb[obase + DH + lane] = (__bf16)(v1q * sq);
    kb[obase + DH + lane] = (__bf16)(v1k * sk);
  }
}

// ---------------------------------------------------------------------------
// Fixed-max MFMA flash attention (causal), PAIRED q-tiles (r9/r13 structure:
// TWO barriers per K-tile, single-buffered K/V LDS, per-tile PV loops —
// known good; the r10 single-barrier variant is convicted, do not re-apply).
// Block bx: q-tiles (bx, 31-bx) -> uniform 33 K-iters/block.
// Grid (16, 32) = 512 blocks. LDS = 40 KB.
// ---------------------------------------------------------------------------
#define KS_STR 104   // K LDS row stride
#define VT_STR 72    // V^T / P row stride
__global__ __launch_bounds__(256) void flash_mfma(
    const __bf16* __restrict__ qg, const __bf16* __restrict__ kg,
    const __bf16* __restrict__ vt,  // [b*1024 + h*64 + d][T_]  (V^T)
    __bf16* __restrict__ ao) {
  __shared__ __align__(16) __bf16 Ksh[64 * KS_STR];      // 13312 B
  __shared__ __align__(16) __bf16 Vth[64 * VT_STR];      //  9216 B
  __shared__ __align__(16) __bf16 Psh[8 * 16 * VT_STR];  // 18432 B

  const int hb = blockIdx.y;
  const int bb = hb >> 4, h = hb & 15;
  const int ta = blockIdx.x;                 // light tile 0..15
  const int tb = (T_ / 64 - 1) - ta;         // heavy tile 31..16
  const int w    = threadIdx.x >> 6;
  const int lane = threadIdx.x & 63;
  const int g    = lane >> 4;
  const int ln   = lane & 15;
  const int qwa = ta * 64 + w * 16;
  const int qwb = tb * 64 + w * 16;
  const float scale = 0.10206207261596577f;  // 1/sqrt(96)
  const size_t hbT = (size_t)hb * T_;
  const __bf16* vrow = vt + (size_t)(bb * 1024 + h * 64) * T_;

  int krow[3], kcol[3], vr[2], vc[2];
  #pragma unroll
  for (int it = 0; it < 3; it++) {
    int slot = threadIdx.x + it * 256;
    krow[it] = slot / 12; kcol[it] = slot % 12;
  }
  #pragma unroll
  for (int it = 0; it < 2; it++) {
    int slot = threadIdx.x + it * 256;
    vr[it] = slot >> 3; vc[it] = slot & 7;
  }

  bf16x8 qfa[3], qfb[3];
  #pragma unroll
  for (int s = 0; s < 3; s++) {
    qfa[s] = *(const bf16x8*)(qg + (hbT + qwa + ln) * DQK + s * 32 + g * 8);
    qfb[s] = *(const bf16x8*)(qg + (hbT + qwb + ln) * DQK + s * 32 + g * 8);
  }

  f32x4 oa[4], ob[4];
  #pragma unroll
  for (int nt = 0; nt < 4; nt++) {
    oa[nt] = (f32x4){0.f, 0.f, 0.f, 0.f};
    ob[nt] = (f32x4){0.f, 0.f, 0.f, 0.f};
  }
  float la[4] = {}, lb[4] = {};

  __bf16* Pb = Psh + w * 16 * VT_STR;
  __bf16* Pa = Psh + (4 + w) * 16 * VT_STR;
  const int kmax = (tb + 1) * 64;            // b is the longer range

  bf16x8 kreg[3], vreg[2];
  #pragma unroll
  for (int it = 0; it < 3; it++)
    kreg[it] = *(const bf16x8*)(kg + (hbT + krow[it]) * DQK + kcol[it] * 8);
  #pragma unroll
  for (int it = 0; it < 2; it++)
    vreg[it] = *(const bf16x8*)(vrow + (size_t)vr[it] * T_ + vc[it] * 8);

  for (int k0 = 0; k0 < kmax; k0 += 64) {
    __syncthreads();   // previous compute done reading Ksh/Vth
    #pragma unroll
    for (int it = 0; it < 3; it++)
      *(bf16x8*)(Ksh + krow[it] * KS_STR + kcol[it] * 8) = kreg[it];
    #pragma unroll
    for (int it = 0; it < 2; it++)
      *(bf16x8*)(Vth + vr[it] * VT_STR + vc[it] * 8) = vreg[it];
    __syncthreads();
    if (k0 + 64 < kmax) {   // prefetch next tile into regs (hidden by compute)
      #pragma unroll
      for (int it = 0; it < 3; it++)
        kreg[it] = *(const bf16x8*)(kg + (hbT + k0 + 64 + krow[it]) * DQK + kcol[it] * 8);
      #pragma unroll
      for (int it = 0; it < 2; it++)
        vreg[it] = *(const bf16x8*)(vrow + (size_t)vr[it] * T_ + k0 + 64 + vc[it] * 8);
    }

    const bool ca = (k0 <= qwa + 15);   // light tile active (wave-uniform)

    f32x4 sa[4], sb[4];
    #pragma unroll
    for (int ks = 0; ks < 4; ks++) {
      sa[ks] = (f32x4){0.f, 0.f, 0.f, 0.f};
      sb[ks] = (f32x4){0.f, 0.f, 0.f, 0.f};
    }
    if (ca) {
      #pragma unroll
      for (int s = 0; s < 3; s++)
        #pragma unroll
        for (int ks = 0; ks < 4; ks++) {
          bf16x8 kf = *(const bf16x8*)(Ksh + (ks * 16 + ln) * KS_STR + s * 32 + g * 8);
          sb[ks] = MFMA16(qfb[s], kf, sb[ks]);
          sa[ks] = MFMA16(qfa[s], kf, sa[ks]);
        }
    } else {
      #pragma unroll
      for (int s = 0; s < 3; s++)
        #pragma unroll
        for (int ks = 0; ks < 4; ks++) {
          bf16x8 kf = *(const bf16x8*)(Ksh + (ks * 16 + ln) * KS_STR + s * 32 + g * 8);
          sb[ks] = MFMA16(qfb[s], kf, sb[ks]);
        }
    }

    // tile b: exp + P + PV (always active: k0 <= tb*64 <= qwb+15)
    {
      const bool diag = (k0 + 63 > qwb);
      #pragma unroll
      for (int ks = 0; ks < 4; ks++)
        #pragma unroll
        for (int r = 0; r < 4; r++) {
          float p = __expf(sb[ks][r] * scale);
          if (diag) {
            int q   = qwb + g * 4 + r;
            int key = k0 + ks * 16 + ln;
            if (key > q) p = 0.f;
          }
          lb[r] += p;
          Pb[(g * 4 + r) * VT_STR + ks * 16 + ln] = (__bf16)p;
        }
      #pragma unroll
      for (int ks2 = 0; ks2 < 2; ks2++) {
        bf16x8 pf = *(const bf16x8*)(Pb + ln * VT_STR + ks2 * 32 + g * 8);
        #pragma unroll
        for (int nt = 0; nt < 4; nt++) {
          bf16x8 vf = *(const bf16x8*)(Vth + (nt * 16 + ln) * VT_STR + ks2 * 32 + g * 8);
          ob[nt] = MFMA16(pf, vf, ob[nt]);
        }
      }
    }

    // tile a: exp + P + PV (only while in range)
    if (ca) {
      const bool diag = (k0 + 63 > qwa);
      #pragma unroll
      for (int ks = 0; ks < 4; ks++)
        #pragma unroll
        for (int r = 0; r < 4; r++) {
          float p = __expf(sa[ks][r] * scale);
          if (diag) {
            int q   = qwa + g * 4 + r;
            int key = k0 + ks * 16 + ln;
            if (key > q) p = 0.f;
          }
          la[r] += p;
          Pa[(g * 4 + r) * VT_STR + ks * 16 + ln] = (__bf16)p;
        }
      #pragma unroll
      for (int ks2 = 0; ks2 < 2; ks2++) {
        bf16x8 pf = *(const bf16x8*)(Pa + ln * VT_STR + ks2 * 32 + g * 8);
        #pragma unroll
        for (int nt = 0; nt < 4; nt++) {
          bf16x8 vf = *(const bf16x8*)(Vth + (nt * 16 + ln) * VT_STR + ks2 * 32 + g * 8);
          oa[nt] = MFMA16(pf, vf, oa[nt]);
        }
      }
    }
  }

  // reduce l across the 16 ln-lanes (g bits untouched by xor 1/2/4/8)
  float lia[4], lib[4];
  #pragma unroll
  for (int r = 0; r < 4; r++) {
    float s = la[r];
    s += __shfl_xor(s, 1); s += __shfl_xor(s, 2);
    s += __shfl_xor(s, 4); s += __shfl_xor(s, 8);
    lia[r] = 1.0f / s;
    float u = lb[r];
    u += __shfl_xor(u, 1); u += __shfl_xor(u, 2);
    u += __shfl_xor(u, 4); u += __shfl_xor(u, 8);
    lib[r] = 1.0f / u;
  }

  #pragma unroll
  for (int nt = 0; nt < 4; nt++)
    #pragma unroll
    for (int r = 0; r < 4; r++) {
      int qa = qwa + g * 4 + r;
      int qb2 = qwb + g * 4 + r;
      ao[(size_t)(bb * T_ + qa) * DM + h * DH + nt * 16 + ln] =
          (__bf16)(oa[nt][r] * lia[r]);
      ao[(size_t)(bb * T_ + qb2) * DM + h * DH + nt * 16 + ln] =
          (__bf16)(ob[nt][r] * lib[r]);
    }
}

// ---------------------------------------------------------------------------
extern "C" void kernel_launch(void* const* d_in, const int* in_sizes, int n_in,
                              void* d_out, int out_size, void* d_ws, size_t ws_size,
                              hipStream_t stream) {
  const float* x     = (const float*)d_in[0];
  const float* w_dq  = (const float*)d_in[1];
  const float* w_uq  = (const float*)d_in[2];
  const float* w_rq  = (const float*)d_in[3];
  const float* w_dkv = (const float*)d_in[4];
  const float* w_rk  = (const float*)d_in[5];
  const float* w_uk  = (const float*)d_in[6];
  const float* w_uv  = (const float*)d_in[7];
  const float* w_o   = (const float*)d_in[8];
  float* out = (float*)d_out;

  __bf16* p = (__bf16*)d_ws;
  __bf16* xb   = p;  p += (size_t)BT * DM;
  __bf16* B1t  = p;  p += (size_t)672 * 1024;
  __bf16* B2t  = p;  p += (size_t)1536 * 384;
  __bf16* B3t  = p;  p += (size_t)2048 * 256;   // w_uk^T | w_uv^T
  __bf16* B4t  = p;  p += (size_t)1024 * 1024;
  __bf16* cqkr = p;  p += (size_t)BT * 672;     // c_q | c_kv | kr
  __bf16* qsqr = p;  p += (size_t)BT * 1536;    // qs | qr
  __bf16* kv   = p;  p += (size_t)BT * 1024;    // ks
  __bf16* vt   = p;  p += (size_t)BT * 1024;    // V^T [b*1024+h*64+d][T]
  __bf16* qb   = p;  p += (size_t)B_ * NH * T_ * DQK;
  __bf16* kb   = p;  p += (size_t)B_ * NH * T_ * DQK;
  __bf16* aob  = xb;   // xb dead after G1

  // Prep: cast x; fused transpose of all 8 weights
  cast_f32_bf16<<<(BT * DM) / 1024, 256, 0, stream>>>(x, xb);
  {
    TDescs td;
    const float* srcs[8] = {w_dq, w_dkv, w_rk, w_uq, w_rq, w_uk, w_uv, w_o};
    __bf16* dsts[8] = {B1t, B1t + (size_t)384 * 1024, B1t + (size_t)640 * 1024,
                       B2t, B2t + (size_t)1024 * 384,
                       B3t, B3t + (size_t)1024 * 256, B4t};
    int Ks[8] = {1024, 1024, 1024, 384, 384, 256, 256, 1024};
    int Ns[8] = {384, 256, 32, 1024, 512, 1024, 1024, 1024};
    int acc = 0;
    for (int i = 0; i < 8; i++) {
      td.src[i] = srcs[i]; td.dst[i] = dsts[i];
      td.K[i] = Ks[i]; td.N[i] = Ns[i];
      td.t0[i] = acc;
      acc += (Ks[i] / 32) * (Ns[i] / 32);
    }
    td.t0[8] = acc;
    transpose_cast_all<<<acc, dim3(32, 8), 0, stream>>>(td);
  }

  // G1: cqkr = xb @ B1t^T   (64x64, BK=64: 704 blocks)
  {
    GemmBatch g; g.nd = 1;
    g.d[0] = GemmDesc{xb, B1t, (void*)cqkr, DM, 1024, 672, 1024, 672, 11, 0};
    gemm_multi<__bf16, 64, 64><<<704, 256, 0, stream>>>(g);
  }
  // Fused: G2 (qsqr), G3 (ks), VT batch 0/1  (64x128, BK=64: 1792 blocks)
  {
    GemmBatch g; g.nd = 4;
    g.d[0] = GemmDesc{cqkr, B2t, (void*)qsqr, 672, 384, 1536, 384, 1536, 12, 0};
    g.d[1] = GemmDesc{cqkr + 384, B3t, (void*)kv, 672, 256, 1024, 256, 1024, 8, 768};
    g.d[2] = GemmDesc{B3t + (size_t)1024 * 256, cqkr + 384, (void*)vt,
                      256, 672, T_, 256, T_, 16, 1280};
    g.d[3] = GemmDesc{B3t + (size_t)1024 * 256, cqkr + (size_t)T_ * 672 + 384,
                      (void*)(vt + (size_t)1024 * T_), 256, 672, T_, 256, T_, 16, 1536};
    gemm_multi<__bf16, 64, 128><<<1792, 256, 0, stream>>>(g);
  }

  // RoPE + concat + RMS-norm
  assemble_qk<<<(BT * NH) / 4, 256, 0, stream>>>(qsqr, kv, cqkr, qb, kb);

  // Paired-tile fixed-max causal MFMA flash attention -> bf16 ao
  flash_mfma<<<dim3(T_ / 128, B_ * NH), 256, 0, stream>>>(qb, kb, vt, aob);

  // G4: out = aob @ B4t^T  (fp32 out, 64x64, BK=64: 1024 blocks)
  {
    GemmBatch g; g.nd = 1;
    g.d[0] = GemmDesc{aob, B4t, (void*)out, DM, 1024, DM, 1024, 1024, 16, 0};
    gemm_multi<float, 64, 64><<<1024, 256, 0, stream>>>(g);
  }
}

// Round 15
// 236.385 us; speedup vs baseline: 1.0457x; 1.0181x over previous
//
#include <hip/hip_runtime.h>
#include <cstdint>
#include <cstddef>
#include <math.h>

#define B_   2
#define T_   2048
#define DM   1024
#define NH   16
#define DH   64
#define DC1  384
#define DCC  256
#define DR   32
#define BT   (B_*T_)
#define DQK  96      // DH + DR

typedef __bf16 bf16x8 __attribute__((ext_vector_type(8)));
typedef __bf16 bf16x4 __attribute__((ext_vector_type(4)));
typedef float  f32x4  __attribute__((ext_vector_type(4)));
#define MFMA16(a,b,c) __builtin_amdgcn_mfma_f32_16x16x32_bf16((a),(b),(c),0,0,0)

__device__ __forceinline__ void gld16(const __bf16* g, __bf16* l) {
  __builtin_amdgcn_global_load_lds(
      (const __attribute__((address_space(1))) void*)g,
      (__attribute__((address_space(3))) void*)l, 16, 0, 0);
}

// ---------------------------------------------------------------------------
// Multi-GEMM, single-barrier double-buffered gld16 pipeline, BK=64.
// PROVEN CORRECT (r10/r11 vs r12 bit-identical outputs). Unchanged from r14.
// ---------------------------------------------------------------------------
struct GemmDesc {
  const __bf16* A;
  const __bf16* Bt;
  void* C;
  int lda, ldb, ldc, K, Nvalid, ntx, blk0;
};
struct GemmBatch { GemmDesc d[4]; int nd; };

template<typename CT, int TM, int TN>
__global__ __launch_bounds__(256) void gemm_multi(GemmBatch gb) {
  constexpr int MT  = TM / 32;
  constexpr int NT  = TN / 32;
  constexpr int APW = (TM * 4) / 256;
  constexpr int BPW = (TN * 4) / 256;
  __shared__ __align__(16) __bf16 As[4 * TM * 32];
  __shared__ __align__(16) __bf16 Bs[4 * TN * 32];
  const int bid = blockIdx.x;
  int di = gb.nd - 1;
  while (di > 0 && bid < gb.d[di].blk0) di--;
  const GemmDesc D = gb.d[di];
  const int local = bid - D.blk0;
  const int by = local / D.ntx, bx = local - by * D.ntx;
  const int m0 = by * TM, n0 = bx * TN;

  const int tid = threadIdx.x;
  const int w = tid >> 6, l = tid & 63;
  const int g = l >> 4, ln = l & 15;
  const int wm = w >> 1, wn = w & 1;

  const __bf16* gA[APW]; int aoff[APW];
  #pragma unroll
  for (int i = 0; i < APW; i++) {
    int slot = w * (APW * 64) + i * 64 + l;
    gA[i] = D.A + (size_t)(m0 + (slot >> 2)) * D.lda + (slot & 3) * 8;
    aoff[i] = (w * (APW * 64) + i * 64) * 8;
  }
  const __bf16* gB[BPW]; int boff[BPW];
  #pragma unroll
  for (int i = 0; i < BPW; i++) {
    int slot = w * (BPW * 64) + i * 64 + l;
    int bn = n0 + (slot >> 2); if (bn >= D.Nvalid) bn = D.Nvalid - 1;
    gB[i] = D.Bt + (size_t)bn * D.ldb + (slot & 3) * 8;
    boff[i] = (w * (BPW * 64) + i * 64) * 8;
  }

  f32x4 acc[MT][NT];
  #pragma unroll
  for (int i = 0; i < MT; i++)
    #pragma unroll
    for (int j = 0; j < NT; j++) acc[i][j] = (f32x4){0.f, 0.f, 0.f, 0.f};

  #pragma unroll
  for (int ch = 0; ch < 2; ch++) {
    #pragma unroll
    for (int i = 0; i < APW; i++)
      gld16(gA[i] + ch * 32, As + ch * TM * 32 + aoff[i]);
    #pragma unroll
    for (int i = 0; i < BPW; i++)
      gld16(gB[i] + ch * 32, Bs + ch * TN * 32 + boff[i]);
  }

  const int nper = D.K >> 6;
  int p = 0;
  for (int it = 0; it < nper; ++it) {
    __syncthreads();
    if (it + 1 < nper) {
      const int ko = (it + 1) * 64;
      #pragma unroll
      for (int ch = 0; ch < 2; ch++) {
        #pragma unroll
        for (int i = 0; i < APW; i++)
          gld16(gA[i] + ko + ch * 32, As + ((p ^ 1) * 2 + ch) * TM * 32 + aoff[i]);
        #pragma unroll
        for (int i = 0; i < BPW; i++)
          gld16(gB[i] + ko + ch * 32, Bs + ((p ^ 1) * 2 + ch) * TN * 32 + boff[i]);
      }
    }
    #pragma unroll
    for (int ch = 0; ch < 2; ch++) {
      bf16x8 af[MT], bfr[NT];
      #pragma unroll
      for (int mt = 0; mt < MT; mt++)
        af[mt] = *(const bf16x8*)(As + (p * 2 + ch) * TM * 32 +
                                  (wm * (TM/2) + mt * 16 + ln) * 32 + g * 8);
      #pragma unroll
      for (int nt = 0; nt < NT; nt++)
        bfr[nt] = *(const bf16x8*)(Bs + (p * 2 + ch) * TN * 32 +
                                   (wn * (TN/2) + nt * 16 + ln) * 32 + g * 8);
      #pragma unroll
      for (int mt = 0; mt < MT; mt++)
        #pragma unroll
        for (int nt = 0; nt < NT; nt++)
          acc[mt][nt] = MFMA16(af[mt], bfr[nt], acc[mt][nt]);
    }
    p ^= 1;
  }

  CT* C = (CT*)D.C;
  #pragma unroll
  for (int mt = 0; mt < MT; mt++)
    #pragma unroll
    for (int r = 0; r < 4; r++) {
      int m = m0 + wm * (TM/2) + mt * 16 + g * 4 + r;
      #pragma unroll
      for (int nt = 0; nt < NT; nt++) {
        int n = n0 + wn * (TN/2) + nt * 16 + ln;
        if (n < D.Nvalid) C[(size_t)m * D.ldc + n] = (CT)acc[mt][nt][r];
      }
    }
}

// ---------------------------------------------------------------------------
// Fused weight prep: 8 matrices fp32 [K,N] -> bf16 transposed [N,K].
// ---------------------------------------------------------------------------
struct TDescs {
  const float* src[8];
  __bf16* dst[8];
  int K[8];
  int N[8];
  int t0[9];
};

__global__ __launch_bounds__(256) void transpose_cast_all(TDescs td) {
  __shared__ float t[32][33];
  int bx = blockIdx.x;
  int i = 7;
  while (bx < td.t0[i]) i--;
  int local = bx - td.t0[i];
  int ntn = td.N[i] >> 5;
  int kt = local / ntn;
  int nt = local - kt * ntn;
  const int ks = kt * 32, ns = nt * 32;
  const float* src = td.src[i];
  __bf16* dst = td.dst[i];
  const int K = td.K[i], N = td.N[i];
  const int tx = threadIdx.x, ty = threadIdx.y;
  #pragma unroll
  for (int r = 0; r < 4; r++)
    t[ty + r * 8][tx] = src[(size_t)(ks + ty + r * 8) * N + ns + tx];
  __syncthreads();
  #pragma unroll
  for (int r = 0; r < 4; r++)
    dst[(size_t)(ns + ty + r * 8) * K + ks + tx] = (__bf16)t[tx][ty + r * 8];
  (void)K;
}

__global__ __launch_bounds__(256) void cast_f32_bf16(
    const float* __restrict__ src, __bf16* __restrict__ dst) {
  int i = (blockIdx.x * 256 + threadIdx.x) * 4;
  float4 v = *(const float4*)(src + i);
  bf16x4 o = { (__bf16)v.x, (__bf16)v.y, (__bf16)v.z, (__bf16)v.w };
  *(bf16x4*)(dst + i) = o;
}

// ---------------------------------------------------------------------------
// Assemble: per (row, head) wave -> RoPE + concat + RMS-norm.
// ---------------------------------------------------------------------------
__global__ __launch_bounds__(256) void assemble_qk(
    const __bf16* __restrict__ qsqr,  // [BT][1536]: qs | qr
    const __bf16* __restrict__ kv,    // [BT][1024]: ks
    const __bf16* __restrict__ cqkr,  // [BT][672]: kr at cols 640..671
    __bf16* __restrict__ qb, __bf16* __restrict__ kb) {
  int wid  = (blockIdx.x * blockDim.x + threadIdx.x) >> 6;
  int lane = threadIdx.x & 63;
  int h   = wid & (NH - 1);
  int row = wid >> 4;
  int b   = row >> 11;
  int t   = row & (T_ - 1);

  float v0q = (float)qsqr[(size_t)row * 1536 + h * DH + lane];
  float v0k = (float)kv[(size_t)row * 1024 + h * DH + lane];
  float v1q = 0.f, v1k = 0.f;
  if (lane < DR) {
    int j  = lane;
    int jj = j & 15;
    float invf = powf(10000.f, -(float)jj / 16.f);
    float ang  = (float)t * invf;
    float s, c;
    sincosf(ang, &s, &c);
    float qx1 = (float)qsqr[(size_t)row * 1536 + 1024 + h * DR + jj];
    float qx2 = (float)qsqr[(size_t)row * 1536 + 1024 + h * DR + 16 + jj];
    float kx1 = (float)cqkr[(size_t)row * 672 + 640 + jj];
    float kx2 = (float)cqkr[(size_t)row * 672 + 640 + 16 + jj];
    if (j < 16) { v1q = qx1 * c - qx2 * s; v1k = kx1 * c - kx2 * s; }
    else        { v1q = qx1 * s + qx2 * c; v1k = kx1 * s + kx2 * c; }
  }
  float ssq = v0q * v0q + v1q * v1q;
  float ssk = v0k * v0k + v1k * v1k;
  #pragma unroll
  for (int off = 32; off; off >>= 1) {
    ssq += __shfl_xor(ssq, off);
    ssk += __shfl_xor(ssk, off);
  }
  float sq = rsqrtf(ssq / 96.f + 1e-6f);
  float sk = rsqrtf(ssk / 96.f + 1e-6f);
  size_t obase = ((size_t)(b * NH + h) * T_ + t) * DQK;
  qb[obase + lane] = (__bf16)(v0q * sq);
  kb[obase + lane] = (__bf16)(v0k * sk);
  if (lane < DR) {
    qb[obase + DH + lane] = (__bf16)(v1q * sq);
    kb[obase + DH + lane] = (__bf16)(v1k * sk);
  }
}

// ---------------------------------------------------------------------------
// Fixed-max MFMA flash attention (causal), paired q-tiles, 8-WAVE blocks.
// Same proven compute structure as r9/r13/r14 (two barriers per K-tile,
// single-buffered K/V, per-tile exp/P/PV), but the block is 512 threads:
// waves 0-3 own the heavy tile tb (16q each), waves 4-7 own the light tile
// ta. Per-wave work halves, waves/CU double (2 blk x 8 w = 16 waves/CU =
// 4 waves/SIMD vs 2 before) -> cross-wave MFMA/VALU phase overlap.
// Uniform 33 K-iters/block preserved. Grid (16, 32) = 512 blocks. LDS 40 KB.
// ---------------------------------------------------------------------------
#define KS_STR 104   // K LDS row stride
#define VT_STR 72    // V^T / P row stride
__global__ __launch_bounds__(512) void flash_mfma(
    const __bf16* __restrict__ qg, const __bf16* __restrict__ kg,
    const __bf16* __restrict__ vt,  // [b*1024 + h*64 + d][T_]  (V^T)
    __bf16* __restrict__ ao) {
  __shared__ __align__(16) __bf16 Ksh[64 * KS_STR];      // 13312 B
  __shared__ __align__(16) __bf16 Vth[64 * VT_STR];      //  9216 B
  __shared__ __align__(16) __bf16 Psh[8 * 16 * VT_STR];  // 18432 B

  const int hb = blockIdx.y;
  const int bb = hb >> 4, h = hb & 15;
  const int ta = blockIdx.x;                 // light tile 0..15
  const int tb = (T_ / 64 - 1) - ta;         // heavy tile 31..16
  const int w    = threadIdx.x >> 6;         // 0..7
  const int lane = threadIdx.x & 63;
  const int g    = lane >> 4;
  const int ln   = lane & 15;
  const int wi   = w & 3;
  const int tile = (w < 4) ? tb : ta;        // wave's tile
  const int qw   = tile * 64 + wi * 16;      // wave's 16 queries
  const float scale = 0.10206207261596577f;  // 1/sqrt(96)
  const size_t hbT = (size_t)hb * T_;
  const __bf16* vrow = vt + (size_t)(bb * 1024 + h * 64) * T_;

  // staging slots for 512 threads: K = 768 bf16x8 slots (1 + guarded half),
  // V = 512 slots (exactly 1 per thread)
  const int ks0   = threadIdx.x;
  const int krow0 = ks0 / 12, kcol0 = ks0 % 12;
  const bool k1on = (threadIdx.x < 256);
  const int ks1   = 512 + threadIdx.x;
  const int krow1 = ks1 / 12, kcol1 = ks1 % 12;
  const int vr = threadIdx.x >> 3, vc = threadIdx.x & 7;

  bf16x8 qf[3];
  #pragma unroll
  for (int s = 0; s < 3; s++)
    qf[s] = *(const bf16x8*)(qg + (hbT + qw + ln) * DQK + s * 32 + g * 8);

  f32x4 o[4];
  #pragma unroll
  for (int nt = 0; nt < 4; nt++) o[nt] = (f32x4){0.f, 0.f, 0.f, 0.f};
  float lsum[4] = {};

  __bf16* Pw = Psh + w * 16 * VT_STR;
  const int kmax = (tb + 1) * 64;

  bf16x8 kreg0, kreg1, vreg;
  kreg0 = *(const bf16x8*)(kg + (hbT + krow0) * DQK + kcol0 * 8);
  if (k1on) kreg1 = *(const bf16x8*)(kg + (hbT + krow1) * DQK + kcol1 * 8);
  vreg = *(const bf16x8*)(vrow + (size_t)vr * T_ + vc * 8);

  for (int k0 = 0; k0 < kmax; k0 += 64) {
    __syncthreads();   // previous compute done reading Ksh/Vth
    *(bf16x8*)(Ksh + krow0 * KS_STR + kcol0 * 8) = kreg0;
    if (k1on) *(bf16x8*)(Ksh + krow1 * KS_STR + kcol1 * 8) = kreg1;
    *(bf16x8*)(Vth + vr * VT_STR + vc * 8) = vreg;
    __syncthreads();
    if (k0 + 64 < kmax) {   // prefetch next tile into regs (hidden by compute)
      kreg0 = *(const bf16x8*)(kg + (hbT + k0 + 64 + krow0) * DQK + kcol0 * 8);
      if (k1on)
        kreg1 = *(const bf16x8*)(kg + (hbT + k0 + 64 + krow1) * DQK + kcol1 * 8);
      vreg = *(const bf16x8*)(vrow + (size_t)vr * T_ + k0 + 64 + vc * 8);
    }

    if (k0 <= qw + 15) {   // wave-uniform causal skip
      // S = Q K^T  (16q x 64k for this wave's tile)
      f32x4 sa[4];
      #pragma unroll
      for (int ks = 0; ks < 4; ks++) sa[ks] = (f32x4){0.f, 0.f, 0.f, 0.f};
      #pragma unroll
      for (int s = 0; s < 3; s++)
        #pragma unroll
        for (int ks = 0; ks < 4; ks++) {
          bf16x8 kf = *(const bf16x8*)(Ksh + (ks * 16 + ln) * KS_STR + s * 32 + g * 8);
          sa[ks] = MFMA16(qf[s], kf, sa[ks]);
        }
      // p = exp(s*scale); mask on diagonal tiles; accumulate l; store P
      const bool diag = (k0 + 63 > qw);
      #pragma unroll
      for (int ks = 0; ks < 4; ks++)
        #pragma unroll
        for (int r = 0; r < 4; r++) {
          float p = __expf(sa[ks][r] * scale);
          if (diag) {
            int q   = qw + g * 4 + r;
            int key = k0 + ks * 16 + ln;
            if (key > q) p = 0.f;
          }
          lsum[r] += p;
          Pw[(g * 4 + r) * VT_STR + ks * 16 + ln] = (__bf16)p;
        }
      // O += P V^T
      #pragma unroll
      for (int ks2 = 0; ks2 < 2; ks2++) {
        bf16x8 pf = *(const bf16x8*)(Pw + ln * VT_STR + ks2 * 32 + g * 8);
        #pragma unroll
        for (int nt = 0; nt < 4; nt++) {
          bf16x8 vf = *(const bf16x8*)(Vth + (nt * 16 + ln) * VT_STR + ks2 * 32 + g * 8);
          o[nt] = MFMA16(pf, vf, o[nt]);
        }
      }
    }
  }

  // reduce l across the 16 ln-lanes (g bits untouched by xor 1/2/4/8)
  float linv[4];
  #pragma unroll
  for (int r = 0; r < 4; r++) {
    float s = lsum[r];
    s += __shfl_xor(s, 1); s += __shfl_xor(s, 2);
    s += __shfl_xor(s, 4); s += __shfl_xor(s, 8);
    linv[r] = 1.0f / s;
  }

  #pragma unroll
  for (int nt = 0; nt < 4; nt++)
    #pragma unroll
    for (int r = 0; r < 4; r++) {
      int q = qw + g * 4 + r;
      ao[(size_t)(bb * T_ + q) * DM + h * DH + nt * 16 + ln] =
          (__bf16)(o[nt][r] * linv[r]);
    }
}

// ---------------------------------------------------------------------------
extern "C" void kernel_launch(void* const* d_in, const int* in_sizes, int n_in,
                              void* d_out, int out_size, void* d_ws, size_t ws_size,
                              hipStream_t stream) {
  const float* x     = (const float*)d_in[0];
  const float* w_dq  = (const float*)d_in[1];
  const float* w_uq  = (const float*)d_in[2];
  const float* w_rq  = (const float*)d_in[3];
  const float* w_dkv = (const float*)d_in[4];
  const float* w_rk  = (const float*)d_in[5];
  const float* w_uk  = (const float*)d_in[6];
  const float* w_uv  = (const float*)d_in[7];
  const float* w_o   = (const float*)d_in[8];
  float* out = (float*)d_out;

  __bf16* p = (__bf16*)d_ws;
  __bf16* xb   = p;  p += (size_t)BT * DM;
  __bf16* B1t  = p;  p += (size_t)672 * 1024;
  __bf16* B2t  = p;  p += (size_t)1536 * 384;
  __bf16* B3t  = p;  p += (size_t)2048 * 256;   // w_uk^T | w_uv^T
  __bf16* B4t  = p;  p += (size_t)1024 * 1024;
  __bf16* cqkr = p;  p += (size_t)BT * 672;     // c_q | c_kv | kr
  __bf16* qsqr = p;  p += (size_t)BT * 1536;    // qs | qr
  __bf16* kv   = p;  p += (size_t)BT * 1024;    // ks
  __bf16* vt   = p;  p += (size_t)BT * 1024;    // V^T [b*1024+h*64+d][T]
  __bf16* qb   = p;  p += (size_t)B_ * NH * T_ * DQK;
  __bf16* kb   = p;  p += (size_t)B_ * NH * T_ * DQK;
  __bf16* aob  = xb;   // xb dead after G1

  // Prep: cast x; fused transpose of all 8 weights
  cast_f32_bf16<<<(BT * DM) / 1024, 256, 0, stream>>>(x, xb);
  {
    TDescs td;
    const float* srcs[8] = {w_dq, w_dkv, w_rk, w_uq, w_rq, w_uk, w_uv, w_o};
    __bf16* dsts[8] = {B1t, B1t + (size_t)384 * 1024, B1t + (size_t)640 * 1024,
                       B2t, B2t + (size_t)1024 * 384,
                       B3t, B3t + (size_t)1024 * 256, B4t};
    int Ks[8] = {1024, 1024, 1024, 384, 384, 256, 256, 1024};
    int Ns[8] = {384, 256, 32, 1024, 512, 1024, 1024, 1024};
    int acc = 0;
    for (int i = 0; i < 8; i++) {
      td.src[i] = srcs[i]; td.dst[i] = dsts[i];
      td.K[i] = Ks[i]; td.N[i] = Ns[i];
      td.t0[i] = acc;
      acc += (Ks[i] / 32) * (Ns[i] / 32);
    }
    td.t0[8] = acc;
    transpose_cast_all<<<acc, dim3(32, 8), 0, stream>>>(td);
  }

  // G1: cqkr = xb @ B1t^T   (64x64, BK=64: 704 blocks)
  {
    GemmBatch g; g.nd = 1;
    g.d[0] = GemmDesc{xb, B1t, (void*)cqkr, DM, 1024, 672, 1024, 672, 11, 0};
    gemm_multi<__bf16, 64, 64><<<704, 256, 0, stream>>>(g);
  }
  // Fused: G2 (qsqr), G3 (ks), VT batch 0/1  (64x128, BK=64: 1792 blocks)
  {
    GemmBatch g; g.nd = 4;
    g.d[0] = GemmDesc{cqkr, B2t, (void*)qsqr, 672, 384, 1536, 384, 1536, 12, 0};
    g.d[1] = GemmDesc{cqkr + 384, B3t, (void*)kv, 672, 256, 1024, 256, 1024, 8, 768};
    g.d[2] = GemmDesc{B3t + (size_t)1024 * 256, cqkr + 384, (void*)vt,
                      256, 672, T_, 256, T_, 16, 1280};
    g.d[3] = GemmDesc{B3t + (size_t)1024 * 256, cqkr + (size_t)T_ * 672 + 384,
                      (void*)(vt + (size_t)1024 * T_), 256, 672, T_, 256, T_, 16, 1536};
    gemm_multi<__bf16, 64, 128><<<1792, 256, 0, stream>>>(g);
  }

  // RoPE + concat + RMS-norm
  assemble_qk<<<(BT * NH) / 4, 256, 0, stream>>>(qsqr, kv, cqkr, qb, kb);

  // Paired-tile fixed-max causal MFMA flash attention (8-wave blocks)
  flash_mfma<<<dim3(T_ / 128, B_ * NH), 512, 0, stream>>>(qb, kb, vt, aob);

  // G4: out = aob @ B4t^T  (fp32 out, 64x64, BK=64: 1024 blocks)
  {
    GemmBatch g; g.nd = 1;
    g.d[0] = GemmDesc{aob, B4t, (void*)out, DM, 1024, DM, 1024, 1024, 16, 0};
    gemm_multi<float, 64, 64><<<1024, 256, 0, stream>>>(g);
  }
}